// Round 6
// baseline (361.746 us; speedup 1.0000x reference)
//
#include <hip/hip_runtime.h>
#include <stdint.h>

typedef unsigned int u32;
typedef unsigned long long u64;
typedef unsigned short u16;
typedef unsigned char u8;
typedef int intx4 __attribute__((ext_vector_type(4)));
typedef int intx8 __attribute__((ext_vector_type(8)));
typedef float floatx4 __attribute__((ext_vector_type(4)));

#define BATCH 4096
#define IN    2048
#define HID   8192
#define NCLS  1000

// ---------- ws layout (bytes) ----------
#define OFF_ROWKEY 0u                       // u64[4096]      32 KB (fallback)
#define OFF_TOPK   32768u                   // u32[4096*512]   8 MB
#define OFF_X8     8421376u                 // fp8 x           8 MB
#define OFF_WK8    16809984u                // fp8 Wk         16 MB
#define OFF_WGT    33587200u                // fp32 Wg^T   31.25 MB
#define TOTAL_FULL 66355200ull

// ---------- helpers ----------
__device__ __forceinline__ u32 fkey(float f) {          // monotonic float->u32
    u32 u = __float_as_uint(f);
    return (u & 0x80000000u) ? ~u : (u | 0x80000000u);
}
__device__ __forceinline__ float unfkey(u32 k) {
    return __uint_as_float((k & 0x80000000u) ? (k ^ 0x80000000u) : ~k);
}
__device__ __forceinline__ void ce32(u32& a, u32& b) {  // desc compare-exchange (2 ops)
    u32 mx = a > b ? a : b;
    u32 mn = a > b ? b : a;
    a = mx; b = mn;
}

// ---------- prep: convert x & Wk to fp8 e4m3 (unit scale), transpose Wg ----------
__global__ __launch_bounds__(256) void prep_kernel(
    const float* __restrict__ x, const float* __restrict__ Wk,
    const float* __restrict__ Wg,
    u8* __restrict__ x8, u8* __restrict__ wk8, float* __restrict__ WgT)
{
    __shared__ float t[32][33];
    const int bid = blockIdx.x;
    if (bid < 1024) {
        const int gid = bid * 256 + threadIdx.x;
        const int NSX = BATCH * IN / 16;          // 524288
        const int NS  = NSX + HID * IN / 16;      // 1572864
        for (int s = gid; s < NS; s += 1024 * 256) {
            const float4* src; u8* dst;
            if (s < NSX) { src = (const float4*)x + (size_t)s * 4;  dst = x8  + (size_t)s * 16; }
            else { int u = s - NSX; src = (const float4*)Wk + (size_t)u * 4; dst = wk8 + (size_t)u * 16; }
            uint4 o;
            float4 f;
            int p;
            f = src[0];
            p = __builtin_amdgcn_cvt_pk_fp8_f32(f.x, f.y, 0, false);
            p = __builtin_amdgcn_cvt_pk_fp8_f32(f.z, f.w, p, true);  o.x = (u32)p;
            f = src[1];
            p = __builtin_amdgcn_cvt_pk_fp8_f32(f.x, f.y, 0, false);
            p = __builtin_amdgcn_cvt_pk_fp8_f32(f.z, f.w, p, true);  o.y = (u32)p;
            f = src[2];
            p = __builtin_amdgcn_cvt_pk_fp8_f32(f.x, f.y, 0, false);
            p = __builtin_amdgcn_cvt_pk_fp8_f32(f.z, f.w, p, true);  o.z = (u32)p;
            f = src[3];
            p = __builtin_amdgcn_cvt_pk_fp8_f32(f.x, f.y, 0, false);
            p = __builtin_amdgcn_cvt_pk_fp8_f32(f.z, f.w, p, true);  o.w = (u32)p;
            *(uint4*)dst = o;
        }
    } else {
        const int tb = bid - 1024;
        const int bx = (tb & 255) * 32;   // HID
        const int by = (tb >> 8) * 32;    // NCLS
        const int tx = threadIdx.x & 31, ty = threadIdx.x >> 5;  // ty 0..7
        #pragma unroll
        for (int i = 0; i < 32; i += 8) {
            int c = by + ty + i;
            t[ty + i][tx] = (c < NCLS) ? Wg[(size_t)c * HID + bx + tx] : 0.f;
        }
        __syncthreads();
        #pragma unroll
        for (int i = 0; i < 32; i += 8) {
            int c = by + tx;
            if (c < NCLS) WgT[(size_t)(bx + ty + i) * NCLS + by + tx] = t[tx][ty + i];
        }
    }
}

// ---------- fp8 MFMA GEMM: 256x256 block, FOUR waves of 128x128, ILP schedule ----------
// Round-6 diagnosis (from counter arithmetic): SQ_LDS_BANK_CONFLICT is purely
// global_load_lds WRITE cost (r0: 1048576 STG-wave-ops x 8 = 8388608 exactly;
// r4/r5: 524288 x 12 = 6291456 exactly) - reads were never conflicted; all
// read-swizzle work was chasing a phantom. MfmaUtil pinned ~25% because all
// waves phase-lock on shared LDS BW: per K-tile/CU MFMA = 2214cy (MX 16x16x128
// = 34.6cy/SIMD) vs LDS reads 192KB = 1500-2300cy; the pipes alternate
// chip-wide regardless of schedule -> serial ~44% ceiling minus overhead = 25%.
// FIX = cut traffic, not schedule: read traffic per wave = (Mw+Nw)*K.
//   8 waves of 128x64: 192KB/CU/K-tile.  4 waves of 128x128: 128KB (-33%),
//   reads now < MFMA. Enabled by 1 wave/SIMD VGPR budget (512): acc 8x8x4=256
//   + af 64 + bf 32 + addr ~30 = ~385, no spill (guard: WRITE_SIZE ~8.2MB).
// Single-wave ILP: head reads A0-7+B0,B1; per column j: prefetch bf[j+2],
// issue 1 A-stage + 1 B-stage, 8 MFMA (B-prefetch & stages hide under 277cy
// MFMA column). One barrier/K-tile (whole-tile dbuf, same proof as r5).
// Math bit-identical: same fp8 data, same 8-slot XOR swizzle pair (verified
// absmax 0 in r5), same MFMA per accumulator, same top-4 epilogue keys.
#define STG(gsrc, ldsoff) \
    __builtin_amdgcn_global_load_lds((const __attribute__((address_space(1))) u32*)(gsrc), \
        (__attribute__((address_space(3))) u32*)&LDS[ldsoff], 16, 0, 0)

#define RD8(dst, off) { \
    intx4 lo_ = *(const intx4*)&LDS[(off)]; \
    intx4 hi_ = *(const intx4*)&LDS[(off) ^ 16u]; \
    dst = __builtin_shufflevector(lo_, hi_, 0, 1, 2, 3, 4, 5, 6, 7); }

#define MFMA1(A_, B_, C_) C_ = __builtin_amdgcn_mfma_scale_f32_16x16x128_f8f6f4( \
    A_, B_, C_, 0, 0, 0, 0x7F, 0, 0x7F)

__global__ __launch_bounds__(256, 1) void mfma_fp8_gemm_kernel(
    const u8* __restrict__ x8, const u8* __restrict__ wk8,
    u32* __restrict__ topk)
{
    __shared__ __align__(16) u8 LDS[2 * 65536];   // 128 KB (A 32K + B 32K, x2)

    const int tid  = threadIdx.x;
    const int lane = tid & 63;
    const int w    = tid >> 6;                    // 0..3
    // XCD-aware bijective swizzle (512 blocks, 8 XCDs)
    const int bid  = blockIdx.x;
    const int wg   = (bid & 7) * 64 + (bid >> 3);
    const int bxn  = wg & 31;                     // N block 0..31
    const int by   = wg >> 5;                     // M block 0..15
    const int bm   = by * 256;
    const int bn   = bxn * 256;
    const int wrow = (w >> 1) * 128;              // 0 or 128
    const int wcol = (w & 1) * 128;               // 0 or 128
    const int m = lane & 15, q = lane >> 4;

    floatx4 acc[8][8];
    #pragma unroll
    for (int i = 0; i < 8; i++)
        #pragma unroll
        for (int j = 0; j < 8; j++)
            acc[i][j] = (floatx4){0.f, 0.f, 0.f, 0.f};

    // staging: 256 threads cover one 32-row unit (4 KB) per STG; physical 16B
    // chunk p = tid&7 of row srow holds logical chunk p ^ (srow&7)
    const int srow = tid >> 3;                                        // 0..31
    const int soff = ((tid & 7) ^ (srow & 7)) * 16;
    const u8* gxa = x8  + (size_t)(bm + srow) * IN + soff;
    const u8* gwb = wk8 + (size_t)(bn + srow) * IN + soff;
    const u32 ldst = (u32)tid * 16;

    // fragment read: logical chunk c of row r at physical c^(r&7); r&7 = m&7
    const u32 csel = (u32)((((2 * q) ^ (m & 7))) * 16);
    const u32 rdA  = (u32)(wrow + m) * 128u + csel;             // A at +0
    const u32 rdB  = 32768u + (u32)(wcol + m) * 128u + csel;    // B at +32K

    // ---- prologue: stage buf0 fully (16 STG units of 32 rows) ----
    #pragma unroll
    for (int u = 0; u < 8; u++) {
        STG(gxa + (size_t)(u * 32) * IN, (u32)(u * 4096) + ldst);
        STG(gwb + (size_t)(u * 32) * IN, 32768u + (u32)(u * 4096) + ldst);
    }
    asm volatile("s_waitcnt vmcnt(0)" ::: "memory");
    __builtin_amdgcn_s_barrier();

    u32 cb = 0u;
    intx8 af[8], bf[8];

    #pragma unroll 1
    for (int kt = 0; kt < 16; ++kt) {
        const u32 nb = cb ^ 65536u;
        const size_t ko = (size_t)(kt + 1) * 128;
        // head: A fragments + first two B fragments
        #pragma unroll
        for (int i = 0; i < 8; i++) RD8(af[i], cb + rdA + (u32)(i * 2048));
        RD8(bf[0], cb + rdB);
        RD8(bf[1], cb + rdB + 2048u);
        // columns: prefetch bf[j+2] || stage pair j || 8 MFMA
        #pragma unroll
        for (int j = 0; j < 8; j++) {
            if (j < 6) RD8(bf[j + 2], cb + rdB + (u32)((j + 2) * 2048));
            if (kt < 15) {
                STG(gxa + (size_t)(j * 32) * IN + ko, nb + (u32)(j * 4096) + ldst);
                STG(gwb + (size_t)(j * 32) * IN + ko, nb + 32768u + (u32)(j * 4096) + ldst);
            }
            #pragma unroll
            for (int i = 0; i < 8; i++) { MFMA1(af[i], bf[j], acc[i][j]); }
        }
        // single sync: my reads of buf[kt] done (data deps force lgkm),
        // my stages of buf[kt+1] landed (vmcnt), barrier -> all waves agree.
        if (kt < 15) {
            asm volatile("s_waitcnt vmcnt(0)" ::: "memory");
            __builtin_amdgcn_s_barrier();
        }
        cb = nb;
    }

    // epilogue: per-row top-4 (u32 keys) per 64-col group; this wave owns 2 groups
    #pragma unroll
    for (int i = 0; i < 8; i++) {
        #pragma unroll
        for (int r = 0; r < 4; r++) {
            #pragma unroll
            for (int g = 0; g < 2; g++) {
                u32 k0 = (fkey(acc[i][g * 4 + 0][r]) & 0xFFFFFFC0u) | (0u << 4) | (u32)m;
                u32 k1 = (fkey(acc[i][g * 4 + 1][r]) & 0xFFFFFFC0u) | (1u << 4) | (u32)m;
                u32 k2 = (fkey(acc[i][g * 4 + 2][r]) & 0xFFFFFFC0u) | (2u << 4) | (u32)m;
                u32 k3 = (fkey(acc[i][g * 4 + 3][r]) & 0xFFFFFFC0u) | (3u << 4) | (u32)m;
                // sort 4 desc
                ce32(k0, k1); ce32(k2, k3); ce32(k0, k2); ce32(k1, k3); ce32(k1, k2);
                // butterfly top-4 merge over the 16 lanes sharing this row
                #pragma unroll
                for (int off = 1; off < 16; off <<= 1) {
                    u32 b0 = __shfl_xor(k0, off, 64);
                    u32 b1 = __shfl_xor(k1, off, 64);
                    u32 b2 = __shfl_xor(k2, off, 64);
                    u32 b3 = __shfl_xor(k3, off, 64);
                    u32 t0 = k0 > b3 ? k0 : b3;    // bitonic keep-max
                    u32 t1 = k1 > b2 ? k1 : b2;
                    u32 t2 = k2 > b1 ? k2 : b1;
                    u32 t3 = k3 > b0 ? k3 : b0;
                    ce32(t0, t2); ce32(t1, t3); ce32(t0, t1); ce32(t2, t3);
                    k0 = t0; k1 = t1; k2 = t2; k3 = t3;
                }
                if (m == 0) {
                    const int grow  = bm + wrow + i * 16 + q * 4 + r;
                    const int group = bxn * 4 + (w & 1) * 2 + g;   // 0..127
                    uint4 v; v.x = k0; v.y = k1; v.z = k2; v.w = k3;
                    *(uint4*)&topk[(size_t)grow * 512 + group * 4] = v;
                }
            }
        }
    }
}

// ---------- scan: one WAVE per row; ballot compaction; exact rescore; gather ----------
__global__ __launch_bounds__(256) void scan_kernel(
    const u32* __restrict__ topk,
    const float* __restrict__ x, const float* __restrict__ Wk,
    const float* __restrict__ WgT, float* __restrict__ out)
{
    __shared__ u16 cand[4][48];
    const int wv   = threadIdx.x >> 6;
    const int lane = threadIdx.x & 63;
    const int row  = blockIdx.x * 4 + wv;

    const uint4* tp = (const uint4*)(topk + (size_t)row * 512);
    uint4 v0 = tp[lane];        // group = lane
    uint4 v1 = tp[lane + 64];   // group = lane + 64

    // row max (u32 keys are value-ordered; id bits only break near-ties)
    u32 mx = v0.x > v1.x ? v0.x : v1.x;   // slot 0 of each uint4 is its group's max
    #pragma unroll
    for (int off = 1; off < 64; off <<= 1) {
        u32 o = __shfl_xor(mx, off, 64);
        if (o > mx) mx = o;
    }
    const float thr = unfkey(mx & 0xFFFFFFC0u) - 12.0f;

    // ballot-compact in-window candidates into per-wave LDS (no atomics)
    int base = 0;
    const u32 ks[8] = {v0.x, v0.y, v0.z, v0.w, v1.x, v1.y, v1.z, v1.w};
    #pragma unroll
    for (int s = 0; s < 8; s++) {
        const int group = (s < 4) ? lane : (lane + 64);
        const u32 key = ks[s];
        const bool in = unfkey(key & 0xFFFFFFC0u) >= thr;
        const u64 msk = __ballot(in);
        if (in) {
            int rnk = base + __popcll(msk & ((1ull << lane) - 1ull));
            if (rnk < 48)
                cand[wv][rnk] = (u16)(group * 64 + (int)((key >> 4) & 3u) * 16 + (int)(key & 15u));
        }
        base += __popcll(msk);
    }
    const int n = min(base, 48);
    __builtin_amdgcn_wave_barrier();   // keep compiler from sinking LDS reads above writes

    int col;
    if (n <= 1) {
        col = cand[wv][0];   // the max itself is always in-window
    } else {
        // exact fp32 rescore, whole wave per candidate
        const float4* xr = (const float4*)(x + (size_t)row * IN);
        float4 a[8];
        #pragma unroll
        for (int p = 0; p < 8; p++) a[p] = xr[p * 64 + lane];
        u64 best = 0ull;
        for (int c = 0; c < n; c++) {
            const int h = cand[wv][c];
            const float4* wr = (const float4*)(Wk + (size_t)h * IN);
            float s = 0.f;
            #pragma unroll
            for (int p = 0; p < 8; p++) {
                float4 b = wr[p * 64 + lane];
                s += a[p].x * b.x + a[p].y * b.y + a[p].z * b.z + a[p].w * b.w;
            }
            #pragma unroll
            for (int off = 1; off < 64; off <<= 1) s += __shfl_xor(s, off, 64);
            // s identical on all lanes; track best on all lanes (no broadcast needed)
            u64 key = ((u64)fkey(s) << 32) | (u64)(0x1FFFu - (u32)h);  // smaller col wins ties
            if (key > best) best = key;
        }
        col = 0x1FFF - (int)(best & 0xFFFFu);
    }

    // gather: out[row, :] = WgT[col, :]   (both rows 16B-aligned: 1000*4 = 4000 B)
    const float4* src = (const float4*)(WgT + (size_t)col * NCLS);
    float4* dst = (float4*)(out + (size_t)row * NCLS);
    for (int t = lane; t < NCLS / 4; t += 64) dst[t] = src[t];
}

// ---------- round-1 fp32 fallback (used only if ws too small) ----------
__global__ void init_ws_kernel(u64* rowkey) {
    int i = blockIdx.x * blockDim.x + threadIdx.x;
    if (i < BATCH) rowkey[i] = 0ULL;
}

__global__ __launch_bounds__(256) void gemm_argmax_kernel(
    const float* __restrict__ x, const float* __restrict__ Wk,
    u64* __restrict__ rowkey)
{
    __shared__ __align__(16) float As[32 * 64];
    __shared__ __align__(16) float Bs[32 * 64];
    const int tid = threadIdx.x;
    const int bm = blockIdx.y * 64, bn = blockIdx.x * 64;
    const int tx = tid & 15, ty = tid >> 4;
    float acc[4][4];
    #pragma unroll
    for (int i = 0; i < 4; i++)
        #pragma unroll
        for (int j = 0; j < 4; j++) acc[i][j] = 0.f;
    const int r0 = tid >> 3, q0 = tid & 7;
    const int r1 = (tid + 256) >> 3, q1 = (tid + 256) & 7;
    const float* xA0 = &x[(size_t)(bm + r0) * IN + q0 * 4];
    const float* xA1 = &x[(size_t)(bm + r1) * IN + q1 * 4];
    const float* wB0 = &Wk[(size_t)(bn + r0) * IN + q0 * 4];
    const float* wB1 = &Wk[(size_t)(bn + r1) * IN + q1 * 4];
    for (int k0 = 0; k0 < IN; k0 += 32) {
        float4 a0 = *(const float4*)(xA0 + k0);
        float4 a1 = *(const float4*)(xA1 + k0);
        float4 b0 = *(const float4*)(wB0 + k0);
        float4 b1 = *(const float4*)(wB1 + k0);
        __syncthreads();
        As[(q0 * 4 + 0) * 64 + r0] = a0.x; As[(q0 * 4 + 1) * 64 + r0] = a0.y;
        As[(q0 * 4 + 2) * 64 + r0] = a0.z; As[(q0 * 4 + 3) * 64 + r0] = a0.w;
        As[(q1 * 4 + 0) * 64 + r1] = a1.x; As[(q1 * 4 + 1) * 64 + r1] = a1.y;
        As[(q1 * 4 + 2) * 64 + r1] = a1.z; As[(q1 * 4 + 3) * 64 + r1] = a1.w;
        Bs[(q0 * 4 + 0) * 64 + r0] = b0.x; Bs[(q0 * 4 + 1) * 64 + r0] = b0.y;
        Bs[(q0 * 4 + 2) * 64 + r0] = b0.z; Bs[(q0 * 4 + 3) * 64 + r0] = b0.w;
        Bs[(q1 * 4 + 0) * 64 + r1] = b1.x; Bs[(q1 * 4 + 1) * 64 + r1] = b1.y;
        Bs[(q1 * 4 + 2) * 64 + r1] = b1.z; Bs[(q1 * 4 + 3) * 64 + r1] = b1.w;
        __syncthreads();
        #pragma unroll
        for (int k = 0; k < 32; k++) {
            float4 av = *(const float4*)&As[k * 64 + ty * 4];
            float4 bv = *(const float4*)&Bs[k * 64 + tx * 4];
            acc[0][0] += av.x * bv.x; acc[0][1] += av.x * bv.y;
            acc[0][2] += av.x * bv.z; acc[0][3] += av.x * bv.w;
            acc[1][0] += av.y * bv.x; acc[1][1] += av.y * bv.y;
            acc[1][2] += av.y * bv.z; acc[1][3] += av.y * bv.w;
            acc[2][0] += av.z * bv.x; acc[2][1] += av.z * bv.y;
            acc[2][2] += av.z * bv.z; acc[2][3] += av.z * bv.w;
            acc[3][0] += av.w * bv.x; acc[3][1] += av.w * bv.y;
            acc[3][2] += av.w * bv.z; acc[3][3] += av.w * bv.w;
        }
    }
    #pragma unroll
    for (int i = 0; i < 4; i++) {
        const int row = bm + ty * 4 + i;
        u64 best = 0ULL;
        #pragma unroll
        for (int j = 0; j < 4; j++) {
            const int col = bn + tx * 4 + j;
            u64 p = ((u64)fkey(acc[i][j]) << 32) | (u64)(0x1FFFu - (unsigned)col);
            if (p > best) best = p;
        }
        #pragma unroll
        for (int off = 1; off < 16; off <<= 1) {
            u64 other = __shfl_xor(best, off, 64);
            if (other > best) best = other;
        }
        if (tx == 0) atomicMax(&rowkey[row], best);
    }
}

__global__ __launch_bounds__(256) void gather_kernel(
    const u64* __restrict__ rowkey, const float* __restrict__ Wg,
    float* __restrict__ out)
{
    const int b = blockIdx.y;
    const int c = blockIdx.x * 256 + threadIdx.x;
    if (c >= NCLS) return;
    const int col = 0x1FFF - (int)(rowkey[b] & 0xFFFFFFFFu);
    out[(size_t)b * NCLS + c] = Wg[(size_t)c * HID + col];
}

// ---------- launch ----------
extern "C" void kernel_launch(void* const* d_in, const int* in_sizes, int n_in,
                              void* d_out, int out_size, void* d_ws, size_t ws_size,
                              hipStream_t stream) {
    const float* x  = (const float*)d_in[0];
    const float* Wk = (const float*)d_in[1];
    const float* Wg = (const float*)d_in[2];
    float* out = (float*)d_out;
    char* ws = (char*)d_ws;

    if (ws_size >= TOTAL_FULL) {
        u32* topk  = (u32*)(ws + OFF_TOPK);
        u8*  x8    = (u8*)(ws + OFF_X8);
        u8*  wk8   = (u8*)(ws + OFF_WK8);
        float* WgT = (float*)(ws + OFF_WGT);

        hipLaunchKernelGGL(prep_kernel, dim3(1024 + 8192), dim3(256), 0, stream,
                           x, Wk, Wg, x8, wk8, WgT);
        hipLaunchKernelGGL(mfma_fp8_gemm_kernel, dim3(512), dim3(256), 0, stream,
                           x8, wk8, topk);
        hipLaunchKernelGGL(scan_kernel, dim3(BATCH / 4), dim3(256), 0, stream,
                           topk, x, Wk, WgT, out);
    } else {
        u64* rowkey = (u64*)(ws + OFF_ROWKEY);
        hipLaunchKernelGGL(init_ws_kernel, dim3(16), dim3(256), 0, stream, rowkey);
        hipLaunchKernelGGL(gemm_argmax_kernel, dim3(HID / 64, BATCH / 64), dim3(256), 0, stream,
                           x, Wk, rowkey);
        hipLaunchKernelGGL(gather_kernel, dim3(4, BATCH), dim3(256), 0, stream,
                           rowkey, Wg, out);
    }
}

// Round 7
// 304.379 us; speedup vs baseline: 1.1885x; 1.1885x over previous
//
#include <hip/hip_runtime.h>
#include <stdint.h>

typedef unsigned int u32;
typedef unsigned long long u64;
typedef unsigned short u16;
typedef unsigned char u8;
typedef int intx8 __attribute__((ext_vector_type(8)));
typedef float floatx4 __attribute__((ext_vector_type(4)));

#define BATCH 4096
#define IN    2048
#define HID   8192
#define NCLS  1000

// ---------- ws layout (bytes) ----------
#define OFF_ROWKEY 0u                       // u64[4096]      32 KB (fallback)
#define OFF_TOPK   32768u                   // u32[4096*512]   8 MB
#define OFF_X8     8421376u                 // fp8 x           8 MB
#define OFF_WK8    16809984u                // fp8 Wk         16 MB
#define OFF_WGT    33587200u                // fp32 Wg^T   31.25 MB
#define TOTAL_FULL 66355200ull

// ---------- helpers ----------
__device__ __forceinline__ u32 fkey(float f) {          // monotonic float->u32
    u32 u = __float_as_uint(f);
    return (u & 0x80000000u) ? ~u : (u | 0x80000000u);
}
__device__ __forceinline__ float unfkey(u32 k) {
    return __uint_as_float((k & 0x80000000u) ? (k ^ 0x80000000u) : ~k);
}
__device__ __forceinline__ void ce32(u32& a, u32& b) {  // desc compare-exchange (2 ops)
    u32 mx = a > b ? a : b;
    u32 mn = a > b ? b : a;
    a = mx; b = mn;
}

// ---------- prep: convert x & Wk to fp8 e4m3 (unit scale), transpose Wg ----------
// Round-7: cvt grid doubled (1024 -> 2048 blocks, 3 grid-stride iters) for
// better HBM saturation; transpose part unchanged.
__global__ __launch_bounds__(256) void prep_kernel(
    const float* __restrict__ x, const float* __restrict__ Wk,
    const float* __restrict__ Wg,
    u8* __restrict__ x8, u8* __restrict__ wk8, float* __restrict__ WgT)
{
    __shared__ float t[32][33];
    const int bid = blockIdx.x;
    if (bid < 2048) {
        // fp8 conversion: segments of 16 floats -> 16 bytes
        const int gid = bid * 256 + threadIdx.x;
        const int NSX = BATCH * IN / 16;          // 524288
        const int NS  = NSX + HID * IN / 16;      // 1572864
        for (int s = gid; s < NS; s += 2048 * 256) {
            const float4* src; u8* dst;
            if (s < NSX) { src = (const float4*)x + (size_t)s * 4;  dst = x8  + (size_t)s * 16; }
            else { int u = s - NSX; src = (const float4*)Wk + (size_t)u * 4; dst = wk8 + (size_t)u * 16; }
            uint4 o;
            float4 f;
            int p;
            f = src[0];
            p = __builtin_amdgcn_cvt_pk_fp8_f32(f.x, f.y, 0, false);
            p = __builtin_amdgcn_cvt_pk_fp8_f32(f.z, f.w, p, true);  o.x = (u32)p;
            f = src[1];
            p = __builtin_amdgcn_cvt_pk_fp8_f32(f.x, f.y, 0, false);
            p = __builtin_amdgcn_cvt_pk_fp8_f32(f.z, f.w, p, true);  o.y = (u32)p;
            f = src[2];
            p = __builtin_amdgcn_cvt_pk_fp8_f32(f.x, f.y, 0, false);
            p = __builtin_amdgcn_cvt_pk_fp8_f32(f.z, f.w, p, true);  o.z = (u32)p;
            f = src[3];
            p = __builtin_amdgcn_cvt_pk_fp8_f32(f.x, f.y, 0, false);
            p = __builtin_amdgcn_cvt_pk_fp8_f32(f.z, f.w, p, true);  o.w = (u32)p;
            *(uint4*)dst = o;
        }
    } else {
        // Wg transpose tile
        const int tb = bid - 2048;
        const int bx = (tb & 255) * 32;   // HID
        const int by = (tb >> 8) * 32;    // NCLS
        const int tx = threadIdx.x & 31, ty = threadIdx.x >> 5;  // ty 0..7
        #pragma unroll
        for (int i = 0; i < 32; i += 8) {
            int c = by + ty + i;
            t[ty + i][tx] = (c < NCLS) ? Wg[(size_t)c * HID + bx + tx] : 0.f;
        }
        __syncthreads();
        #pragma unroll
        for (int i = 0; i < 32; i += 8) {
            int c = by + tx;
            if (c < NCLS) WgT[(size_t)(bx + ty + i) * NCLS + by + tx] = t[tx][ty + i];
        }
    }
}

// ---------- fp8 MFMA GEMM (16x16x128, unit scales): top-4 u32 keys / 64-col group ----------
// ROUND-7: verbatim revert to the round-0 kernel (best verified: 112 µs,
// absmax 0, VGPR 76, 3 blocks/CU, ~2.4 waves/SIMD). Six structural rewrites
// (ring-3 counted-vmcnt, 8-slot swizzle pipelining, 256^2 4-phase, 1-barrier,
// 128x128-wave ILP) all landed at 108-156 µs: the binding regime is
// latency-hiding via occupancy, and this config's wave count + the compiler's
// own fine-grained lgkmcnt scheduling already deliver the best found point.
__global__ __launch_bounds__(256) void mfma_fp8_gemm_kernel(
    const u8* __restrict__ x8, const u8* __restrict__ wk8,
    u32* __restrict__ topk)
{
    __shared__ __align__(16) u8 At[128 * 128];   // 16 KB
    __shared__ __align__(16) u8 Bt[128 * 128];   // 16 KB

    const int tid  = threadIdx.x;
    const int lane = tid & 63;
    const int w    = tid >> 6;
    const int bm   = blockIdx.y * 128;
    const int bn   = blockIdx.x * 128;
    const int wrow = (w >> 1) * 64, wcol = (w & 1) * 64;
    const int m = lane & 15, q = lane >> 4;

    floatx4 acc[4][4];
    #pragma unroll
    for (int i = 0; i < 4; i++)
        #pragma unroll
        for (int j = 0; j < 4; j++)
            acc[i][j] = (floatx4){0.f, 0.f, 0.f, 0.f};

    // staging: lane covers row (tid>>3); source 16B-chunk permuted so that
    // physical chunk (tid&7) = logical granule ((tid>>1)&3)^(row&3), half (tid&1)
    const int srow = tid >> 3;
    const int soff = (((((tid >> 1) & 3) ^ (srow & 3)) * 2) + (tid & 1)) * 16;
    const u8* gxa = x8  + (size_t)(bm + srow) * IN + soff;
    const u8* gwb = wk8 + (size_t)(bn + srow) * IN + soff;

    // fragment read offset: logical granule q of row (..+m) sits at q^(m&3)
    const int foq = (q ^ (m & 3)) * 32;

    #pragma unroll 1
    for (int k0 = 0; k0 < IN; k0 += 128) {
        #pragma unroll
        for (int s = 0; s < 4; s++) {
            __builtin_amdgcn_global_load_lds(
                (const __attribute__((address_space(1))) u32*)(gxa + k0 + (size_t)s * 32 * IN),
                (__attribute__((address_space(3))) u32*)&At[s * 4096 + tid * 16], 16, 0, 0);
            __builtin_amdgcn_global_load_lds(
                (const __attribute__((address_space(1))) u32*)(gwb + k0 + (size_t)s * 32 * IN),
                (__attribute__((address_space(3))) u32*)&Bt[s * 4096 + tid * 16], 16, 0, 0);
        }
        __syncthreads();   // staging complete

        intx8 af[4];
        #pragma unroll
        for (int i = 0; i < 4; i++)
            af[i] = *(const intx8*)&At[(wrow + i * 16 + m) * 128 + foq];
        #pragma unroll
        for (int j = 0; j < 4; j++) {
            intx8 bf = *(const intx8*)&Bt[(wcol + j * 16 + m) * 128 + foq];
            #pragma unroll
            for (int i = 0; i < 4; i++)
                acc[i][j] = __builtin_amdgcn_mfma_scale_f32_16x16x128_f8f6f4(
                    af[i], bf, acc[i][j],
                    0, 0,            // cbsz=FP8(e4m3), blgp=FP8(e4m3)
                    0, 0x7F,         // opsel_a, scale_a = 2^0
                    0, 0x7F);        // opsel_b, scale_b = 2^0
        }

        __syncthreads();   // reads done before next overwrite
    }

    // epilogue: per-row top-4 (u32 keys) over this wave's 64 columns
    const int group = blockIdx.x * 2 + (wcol >> 6);   // 64-col group id, 0..127
    #pragma unroll
    for (int i = 0; i < 4; i++) {
        #pragma unroll
        for (int r = 0; r < 4; r++) {
            u32 k0 = (fkey(acc[i][0][r]) & 0xFFFFFFC0u) | (0u << 4) | (u32)m;
            u32 k1 = (fkey(acc[i][1][r]) & 0xFFFFFFC0u) | (1u << 4) | (u32)m;
            u32 k2 = (fkey(acc[i][2][r]) & 0xFFFFFFC0u) | (2u << 4) | (u32)m;
            u32 k3 = (fkey(acc[i][3][r]) & 0xFFFFFFC0u) | (3u << 4) | (u32)m;
            // sort 4 desc
            ce32(k0, k1); ce32(k2, k3); ce32(k0, k2); ce32(k1, k3); ce32(k1, k2);
            // butterfly top-4 merge over the 16 lanes sharing this row
            #pragma unroll
            for (int off = 1; off < 16; off <<= 1) {
                u32 b0 = __shfl_xor(k0, off, 64);
                u32 b1 = __shfl_xor(k1, off, 64);
                u32 b2 = __shfl_xor(k2, off, 64);
                u32 b3 = __shfl_xor(k3, off, 64);
                u32 t0 = k0 > b3 ? k0 : b3;    // bitonic keep-max
                u32 t1 = k1 > b2 ? k1 : b2;
                u32 t2 = k2 > b1 ? k2 : b1;
                u32 t3 = k3 > b0 ? k3 : b0;
                ce32(t0, t2); ce32(t1, t3); ce32(t0, t1); ce32(t2, t3);
                k0 = t0; k1 = t1; k2 = t2; k3 = t3;
            }
            if (m == 0) {
                const int grow = bm + wrow + i * 16 + q * 4 + r;
                uint4 v; v.x = k0; v.y = k1; v.z = k2; v.w = k3;
                *(uint4*)&topk[(size_t)grow * 512 + group * 4] = v;
            }
        }
    }
}

// ---------- scan: one WAVE per row; ballot compaction; exact rescore; gather ----------
__global__ __launch_bounds__(256) void scan_kernel(
    const u32* __restrict__ topk,
    const float* __restrict__ x, const float* __restrict__ Wk,
    const float* __restrict__ WgT, float* __restrict__ out)
{
    __shared__ u16 cand[4][48];
    const int wv   = threadIdx.x >> 6;
    const int lane = threadIdx.x & 63;
    const int row  = blockIdx.x * 4 + wv;

    const uint4* tp = (const uint4*)(topk + (size_t)row * 512);
    uint4 v0 = tp[lane];        // group = lane
    uint4 v1 = tp[lane + 64];   // group = lane + 64

    // row max (u32 keys are value-ordered; id bits only break near-ties)
    u32 mx = v0.x > v1.x ? v0.x : v1.x;   // slot 0 of each uint4 is its group's max
    #pragma unroll
    for (int off = 1; off < 64; off <<= 1) {
        u32 o = __shfl_xor(mx, off, 64);
        if (o > mx) mx = o;
    }
    const float thr = unfkey(mx & 0xFFFFFFC0u) - 12.0f;

    // ballot-compact in-window candidates into per-wave LDS (no atomics)
    int base = 0;
    const u32 ks[8] = {v0.x, v0.y, v0.z, v0.w, v1.x, v1.y, v1.z, v1.w};
    #pragma unroll
    for (int s = 0; s < 8; s++) {
        const int group = (s < 4) ? lane : (lane + 64);
        const u32 key = ks[s];
        const bool in = unfkey(key & 0xFFFFFFC0u) >= thr;
        const u64 msk = __ballot(in);
        if (in) {
            int rnk = base + __popcll(msk & ((1ull << lane) - 1ull));
            if (rnk < 48)
                cand[wv][rnk] = (u16)(group * 64 + (int)((key >> 4) & 3u) * 16 + (int)(key & 15u));
        }
        base += __popcll(msk);
    }
    const int n = min(base, 48);
    __builtin_amdgcn_wave_barrier();   // keep compiler from sinking LDS reads above writes

    int col;
    if (n <= 1) {
        col = cand[wv][0];   // the max itself is always in-window
    } else {
        // exact fp32 rescore, whole wave per candidate
        const float4* xr = (const float4*)(x + (size_t)row * IN);
        float4 a[8];
        #pragma unroll
        for (int p = 0; p < 8; p++) a[p] = xr[p * 64 + lane];
        u64 best = 0ull;
        for (int c = 0; c < n; c++) {
            const int h = cand[wv][c];
            const float4* wr = (const float4*)(Wk + (size_t)h * IN);
            float s = 0.f;
            #pragma unroll
            for (int p = 0; p < 8; p++) {
                float4 b = wr[p * 64 + lane];
                s += a[p].x * b.x + a[p].y * b.y + a[p].z * b.z + a[p].w * b.w;
            }
            #pragma unroll
            for (int off = 1; off < 64; off <<= 1) s += __shfl_xor(s, off, 64);
            // s identical on all lanes; track best on all lanes (no broadcast needed)
            u64 key = ((u64)fkey(s) << 32) | (u64)(0x1FFFu - (u32)h);  // smaller col wins ties
            if (key > best) best = key;
        }
        col = 0x1FFF - (int)(best & 0xFFFFu);
    }

    // gather: out[row, :] = WgT[col, :]   (both rows 16B-aligned: 1000*4 = 4000 B)
    const float4* src = (const float4*)(WgT + (size_t)col * NCLS);
    float4* dst = (float4*)(out + (size_t)row * NCLS);
    for (int t = lane; t < NCLS / 4; t += 64) dst[t] = src[t];
}

// ---------- round-1 fp32 fallback (used only if ws too small) ----------
__global__ void init_ws_kernel(u64* rowkey) {
    int i = blockIdx.x * blockDim.x + threadIdx.x;
    if (i < BATCH) rowkey[i] = 0ULL;
}

__global__ __launch_bounds__(256) void gemm_argmax_kernel(
    const float* __restrict__ x, const float* __restrict__ Wk,
    u64* __restrict__ rowkey)
{
    __shared__ __align__(16) float As[32 * 64];
    __shared__ __align__(16) float Bs[32 * 64];
    const int tid = threadIdx.x;
    const int bm = blockIdx.y * 64, bn = blockIdx.x * 64;
    const int tx = tid & 15, ty = tid >> 4;
    float acc[4][4];
    #pragma unroll
    for (int i = 0; i < 4; i++)
        #pragma unroll
        for (int j = 0; j < 4; j++) acc[i][j] = 0.f;
    const int r0 = tid >> 3, q0 = tid & 7;
    const int r1 = (tid + 256) >> 3, q1 = (tid + 256) & 7;
    const float* xA0 = &x[(size_t)(bm + r0) * IN + q0 * 4];
    const float* xA1 = &x[(size_t)(bm + r1) * IN + q1 * 4];
    const float* wB0 = &Wk[(size_t)(bn + r0) * IN + q0 * 4];
    const float* wB1 = &Wk[(size_t)(bn + r1) * IN + q1 * 4];
    for (int k0 = 0; k0 < IN; k0 += 32) {
        float4 a0 = *(const float4*)(xA0 + k0);
        float4 a1 = *(const float4*)(xA1 + k0);
        float4 b0 = *(const float4*)(wB0 + k0);
        float4 b1 = *(const float4*)(wB1 + k0);
        __syncthreads();
        As[(q0 * 4 + 0) * 64 + r0] = a0.x; As[(q0 * 4 + 1) * 64 + r0] = a0.y;
        As[(q0 * 4 + 2) * 64 + r0] = a0.z; As[(q0 * 4 + 3) * 64 + r0] = a0.w;
        As[(q1 * 4 + 0) * 64 + r1] = a1.x; As[(q1 * 4 + 1) * 64 + r1] = a1.y;
        As[(q1 * 4 + 2) * 64 + r1] = a1.z; As[(q1 * 4 + 3) * 64 + r1] = a1.w;
        Bs[(q0 * 4 + 0) * 64 + r0] = b0.x; Bs[(q0 * 4 + 1) * 64 + r0] = b0.y;
        Bs[(q0 * 4 + 2) * 64 + r0] = b0.z; Bs[(q0 * 4 + 3) * 64 + r0] = b0.w;
        Bs[(q1 * 4 + 0) * 64 + r1] = b1.x; Bs[(q1 * 4 + 1) * 64 + r1] = b1.y;
        Bs[(q1 * 4 + 2) * 64 + r1] = b1.z; Bs[(q1 * 4 + 3) * 64 + r1] = b1.w;
        __syncthreads();
        #pragma unroll
        for (int k = 0; k < 32; k++) {
            float4 av = *(const float4*)&As[k * 64 + ty * 4];
            float4 bv = *(const float4*)&Bs[k * 64 + tx * 4];
            acc[0][0] += av.x * bv.x; acc[0][1] += av.x * bv.y;
            acc[0][2] += av.x * bv.z; acc[0][3] += av.x * bv.w;
            acc[1][0] += av.y * bv.x; acc[1][1] += av.y * bv.y;
            acc[1][2] += av.y * bv.z; acc[1][3] += av.y * bv.w;
            acc[2][0] += av.z * bv.x; acc[2][1] += av.z * bv.y;
            acc[2][2] += av.z * bv.z; acc[2][3] += av.z * bv.w;
            acc[3][0] += av.w * bv.x; acc[3][1] += av.w * bv.y;
            acc[3][2] += av.w * bv.z; acc[3][3] += av.w * bv.w;
        }
    }
    #pragma unroll
    for (int i = 0; i < 4; i++) {
        const int row = bm + ty * 4 + i;
        u64 best = 0ULL;
        #pragma unroll
        for (int j = 0; j < 4; j++) {
            const int col = bn + tx * 4 + j;
            u64 p = ((u64)fkey(acc[i][j]) << 32) | (u64)(0x1FFFu - (unsigned)col);
            if (p > best) best = p;
        }
        #pragma unroll
        for (int off = 1; off < 16; off <<= 1) {
            u64 other = __shfl_xor(best, off, 64);
            if (other > best) best = other;
        }
        if (tx == 0) atomicMax(&rowkey[row], best);
    }
}

__global__ __launch_bounds__(256) void gather_kernel(
    const u64* __restrict__ rowkey, const float* __restrict__ Wg,
    float* __restrict__ out)
{
    const int b = blockIdx.y;
    const int c = blockIdx.x * 256 + threadIdx.x;
    if (c >= NCLS) return;
    const int col = 0x1FFF - (int)(rowkey[b] & 0xFFFFFFFFu);
    out[(size_t)b * NCLS + c] = Wg[(size_t)c * HID + col];
}

// ---------- launch ----------
extern "C" void kernel_launch(void* const* d_in, const int* in_sizes, int n_in,
                              void* d_out, int out_size, void* d_ws, size_t ws_size,
                              hipStream_t stream) {
    const float* x  = (const float*)d_in[0];
    const float* Wk = (const float*)d_in[1];
    const float* Wg = (const float*)d_in[2];
    float* out = (float*)d_out;
    char* ws = (char*)d_ws;

    if (ws_size >= TOTAL_FULL) {
        u32* topk  = (u32*)(ws + OFF_TOPK);
        u8*  x8    = (u8*)(ws + OFF_X8);
        u8*  wk8   = (u8*)(ws + OFF_WK8);
        float* WgT = (float*)(ws + OFF_WGT);

        hipLaunchKernelGGL(prep_kernel, dim3(2048 + 8192), dim3(256), 0, stream,
                           x, Wk, Wg, x8, wk8, WgT);
        hipLaunchKernelGGL(mfma_fp8_gemm_kernel, dim3(HID / 128, BATCH / 128), dim3(256), 0, stream,
                           x8, wk8, topk);
        hipLaunchKernelGGL(scan_kernel, dim3(BATCH / 4), dim3(256), 0, stream,
                           topk, x, Wk, WgT, out);
    } else {
        u64* rowkey = (u64*)(ws + OFF_ROWKEY);
        hipLaunchKernelGGL(init_ws_kernel, dim3(16), dim3(256), 0, stream, rowkey);
        hipLaunchKernelGGL(gemm_argmax_kernel, dim3(HID / 64, BATCH / 64), dim3(256), 0, stream,
                           x, Wk, rowkey);
        hipLaunchKernelGGL(gather_kernel, dim3(4, BATCH), dim3(256), 0, stream,
                           rowkey, Wg, out);
    }
}